// Round 1
// baseline (48.046 us; speedup 1.0000x reference)
//
#include <hip/hip_runtime.h>

typedef float  f32x4 __attribute__((ext_vector_type(4)));
typedef short  s16x8 __attribute__((ext_vector_type(8)));

// fp32 -> bf16 round-to-nearest-even
__device__ __forceinline__ unsigned int f2bf(float x) {
    unsigned int u = __float_as_uint(x);
    return (u + 0x7FFFu + ((u >> 16) & 1u)) >> 16;
}

// XOR-swizzled element offset within a [64 rows][64 t] bf16 plane (128B rows).
// Granule = 8 elements (16B). Reads (t mult of 8) and writes (t mult of 4,
// XOR is mult of 8) both stay aligned & bijective.
__device__ __forceinline__ int swz(int row, int t) {
    int g = ((row ^ (row >> 3)) & 7) << 3;
    return row * 64 + (t ^ g);
}

__global__ __launch_bounds__(256, 2)
void upsample_mfma_kernel(const float* __restrict__ yt,
                          const float* __restrict__ Ht,
                          const float* __restrict__ biases,
                          float* __restrict__ out)
{
    // [px'][row][t] bf16 planes, 8KB each
    __shared__ __align__(16) unsigned short Wl[4][4096];  // row = uu
    __shared__ __align__(16) unsigned short Al[4][4096];  // row = b

    // XCD-aware bijective swizzle: 1024 WGs -> chunks of 128 per XCD so the
    // 8 WGs sharing each yt cacheline (same py, adjacent pxg) share an L2.
    const int wg  = blockIdx.x;
    const int nw  = (wg & 7) * 128 + (wg >> 3);
    const int py  = nw >> 4;    // 0..63
    const int pxg = nw & 15;    // 0..15, covers px = pxg*4 .. +3
    const int c0  = pxg * 32;   // full-res col base
    const int tid = threadIdx.x;

    // ---- stage W tile: Ht[t, py*8+uy, c0 + 0..31] -> Wl[px'][uu][t] ----
    {
        const int c4  = tid & 7;          // 16B col group (4 floats)
        const int uy  = (tid >> 3) & 7;
        const int t4l = tid >> 6;
        const float* base = Ht + (py * 8 + uy) * 512 + c0 + c4 * 4;
        #pragma unroll
        for (int pass = 0; pass < 4; ++pass) {
            const int tt4 = (pass << 2) | t4l;        // t-base = tt4*4
            f32x4 v0 = *(const f32x4*)(base + (tt4 * 4 + 0) * 262144);
            f32x4 v1 = *(const f32x4*)(base + (tt4 * 4 + 1) * 262144);
            f32x4 v2 = *(const f32x4*)(base + (tt4 * 4 + 2) * 262144);
            f32x4 v3 = *(const f32x4*)(base + (tt4 * 4 + 3) * 262144);
            #pragma unroll
            for (int cc = 0; cc < 4; ++cc) {
                const int c   = c4 * 4 + cc;
                const int pxl = c >> 3;
                const int uu  = uy * 8 + (c & 7);
                unsigned int lo = f2bf(v0[cc]) | (f2bf(v1[cc]) << 16);
                unsigned int hi = f2bf(v2[cc]) | (f2bf(v3[cc]) << 16);
                *(uint2*)&Wl[pxl][swz(uu, tt4 * 4)] = make_uint2(lo, hi);
            }
        }
    }

    // ---- stage A tile: yt[b, t, py, pxg*4 + 0..3] -> Al[px'][b][t] ----
    {
        const int t4 = tid & 15;
        const int bl = tid >> 4;
        #pragma unroll
        for (int pass = 0; pass < 4; ++pass) {
            const int b = (pass << 4) | bl;           // 0..63
            const float* base = yt + b * 262144 + py * 64 + pxg * 4;
            f32x4 v0 = *(const f32x4*)(base + (t4 * 4 + 0) * 4096);
            f32x4 v1 = *(const f32x4*)(base + (t4 * 4 + 1) * 4096);
            f32x4 v2 = *(const f32x4*)(base + (t4 * 4 + 2) * 4096);
            f32x4 v3 = *(const f32x4*)(base + (t4 * 4 + 3) * 4096);
            #pragma unroll
            for (int pp = 0; pp < 4; ++pp) {
                unsigned int lo = f2bf(v0[pp]) | (f2bf(v1[pp]) << 16);
                unsigned int hi = f2bf(v2[pp]) | (f2bf(v3[pp]) << 16);
                *(uint2*)&Al[pp][swz(b, t4 * 4)] = make_uint2(lo, hi);
            }
        }
    }

    __syncthreads();

    // ---- per-wave 64x64x64 GEMM: D[b][uu] = sum_t A[b][t] * W[t][uu] ----
    const int w  = tid >> 6;          // wave = px'
    const int l  = tid & 63;
    const int r  = l & 15;
    const int q  = l >> 4;
    const int px = pxg * 4 + w;
    const int p  = py * 64 + px;

    f32x4 acc[4][4];
    #pragma unroll
    for (int nb = 0; nb < 4; ++nb) {
        const float bv = biases[p * 64 + nb * 16 + r];
        #pragma unroll
        for (int mb = 0; mb < 4; ++mb)
            acc[mb][nb] = (f32x4){bv, bv, bv, bv};
    }

    #pragma unroll
    for (int ks = 0; ks < 2; ++ks) {
        const int t = ks * 32 + q * 8;   // k = t0 + q*8 + j, j=0..7
        s16x8 af[4], bfv[4];
        #pragma unroll
        for (int mb = 0; mb < 4; ++mb)
            af[mb] = *(const s16x8*)&Al[w][swz(mb * 16 + r, t)];
        #pragma unroll
        for (int nb = 0; nb < 4; ++nb)
            bfv[nb] = *(const s16x8*)&Wl[w][swz(nb * 16 + r, t)];
        #pragma unroll
        for (int mb = 0; mb < 4; ++mb)
            #pragma unroll
            for (int nb = 0; nb < 4; ++nb)
                acc[mb][nb] = __builtin_amdgcn_mfma_f32_16x16x32_bf16(
                    af[mb], bfv[nb], acc[mb][nb], 0, 0, 0);
    }

    // ---- epilogue: pixel-shuffle store. D: col n = l&15, row m = q*4 + i ----
    #pragma unroll
    for (int mb = 0; mb < 4; ++mb) {
        #pragma unroll
        for (int nb = 0; nb < 4; ++nb) {
            const int n   = nb * 16 + r;          // uu
            const int row = py * 8 + (n >> 3);
            const int col = px * 8 + (n & 7);
            #pragma unroll
            for (int i = 0; i < 4; ++i) {
                const int b = mb * 16 + q * 4 + i;
                out[(b * 512 + row) * 512 + col] = acc[mb][nb][i];
            }
        }
    }
}

extern "C" void kernel_launch(void* const* d_in, const int* in_sizes, int n_in,
                              void* d_out, int out_size, void* d_ws, size_t ws_size,
                              hipStream_t stream) {
    const float* yt     = (const float*)d_in[0];
    const float* Ht     = (const float*)d_in[1];
    const float* biases = (const float*)d_in[2];
    float* out          = (float*)d_out;
    upsample_mfma_kernel<<<dim3(1024), dim3(256), 0, stream>>>(yt, Ht, biases, out);
}